// Round 3
// baseline (505.496 us; speedup 1.0000x reference)
//
#include <hip/hip_runtime.h>
#include <hip/hip_bf16.h>
#include <math.h>

// Problem constants: x [8, 96, 256, 256] fp32, window 16x16 -> 2048 windows.
#define NWIN 2048

typedef __bf16 v8bf __attribute__((ext_vector_type(8)));
typedef __bf16 v2bf __attribute__((ext_vector_type(2)));
typedef float  v4f  __attribute__((ext_vector_type(4)));
typedef unsigned int v4u __attribute__((ext_vector_type(4)));

// Kernel 1 (batched): block handles 16 windows (one batch-row of windows),
// staging w_real/car_w1/car_w2 ONCE per block instead of once per window
// (old version re-read 36KB of w_real per window = 2048x).
// pool(real_conv)[o] = sum_c Wr[o,c] * x_win[c,0,0]/16 + b_r[o].
// Block 128 computes the global beta vector from b_imag.
__global__ __launch_bounds__(128) void se_alpha_kernel(
    const float* __restrict__ x,
    const float* __restrict__ w_real, const float* __restrict__ b_real,
    const float* __restrict__ car_w1, const float* __restrict__ car_b1,
    const float* __restrict__ car_w2, const float* __restrict__ car_b2,
    const float* __restrict__ b_imag,
    const float* __restrict__ cai_w1, const float* __restrict__ cai_b1,
    const float* __restrict__ cai_w2, const float* __restrict__ cai_b2,
    float* __restrict__ alpha, float* __restrict__ beta)
{
    __shared__ float wr_s[96 * 97];   // +1 pad
    __shared__ float w1_s[32 * 97];   // car_w1 [32][96]
    __shared__ float w2_s[96 * 33];   // car_w2 [96][32]
    __shared__ float x0_s[96 * 17];   // corner pixel per chan x 16 windows
    __shared__ float pr_s[16 * 97];   // pooled [win][o]
    __shared__ float h1_s[16 * 33];   // hidden [win][j]
    const int t = threadIdx.x;
    const int blkid = blockIdx.x;

    if (blkid < 128) {
        const int b = blkid >> 4, wh = blkid & 15;
        for (int idx = t; idx < 96 * 96; idx += 128) {
            int o = idx / 96, c = idx - o * 96;
            wr_s[o * 97 + c] = w_real[idx];
        }
        for (int idx = t; idx < 32 * 96; idx += 128) {
            int j = idx / 96, c = idx - j * 96;
            w1_s[j * 97 + c] = car_w1[idx];
        }
        for (int idx = t; idx < 96 * 32; idx += 128) {
            int o = idx >> 5, j = idx & 31;
            w2_s[o * 33 + j] = car_w2[idx];
        }
        for (int idx = t; idx < 96 * 16; idx += 128) {
            int c = idx >> 4, w = idx & 15;
            x0_s[c * 17 + w] = x[(((size_t)(b * 96 + c)) * 256 + wh * 16) * 256 + w * 16];
        }
        __syncthreads();
        // pooled: pr[w][o] = (1/16) sum_c Wr[o][c]*x0[c][w] + b_real[o]
        #pragma unroll
        for (int i = 0; i < 12; ++i) {
            int p = t + i * 128;            // 96*16 = 1536
            int o = p >> 4, w = p & 15;
            float acc = 0.f;
            #pragma unroll 4
            for (int c = 0; c < 96; ++c) acc += wr_s[o * 97 + c] * x0_s[c * 17 + w];
            pr_s[w * 97 + o] = acc * (1.0f / 16.0f) + b_real[o];
        }
        __syncthreads();
        // h1[w][j] = relu(sum_o W1[j][o]*pr[w][o] + b1[j])
        #pragma unroll
        for (int i = 0; i < 4; ++i) {
            int p = t + i * 128;            // 32*16 = 512
            int j = p >> 4, w = p & 15;
            float acc = car_b1[j];
            #pragma unroll 4
            for (int o = 0; o < 96; ++o) acc += w1_s[j * 97 + o] * pr_s[w * 97 + o];
            h1_s[w * 33 + j] = fmaxf(acc, 0.f);
        }
        __syncthreads();
        // alpha[n][o] = 1 + sigmoid(sum_j W2[o][j]*h1[w][j] + b2[o])
        #pragma unroll
        for (int i = 0; i < 12; ++i) {
            int p = t + i * 128;            // 96*16 = 1536
            int o = p >> 4, w = p & 15;
            float acc = car_b2[o];
            #pragma unroll
            for (int j = 0; j < 32; ++j) acc += w2_s[o * 33 + j] * h1_s[w * 33 + j];
            int n = (blkid << 4) | w;
            alpha[(size_t)n * 96 + o] = 1.f + 1.f / (1.f + __expf(-acc));
        }
    } else {
        // beta: pooled imag part is exactly b_imag (mean of Im(fft) of real x = 0)
        if (t < 32) {
            float acc = cai_b1[t];
            for (int o = 0; o < 96; ++o) acc += cai_w1[t * 96 + o] * b_imag[o];
            h1_s[t] = fmaxf(acc, 0.f);
        }
        __syncthreads();
        if (t < 96) {
            float acc = cai_b2[t];
            for (int j = 0; j < 32; ++j) acc += cai_w2[t * 32 + j] * h1_s[j];
            beta[t] = 1.f + 1.f / (1.f + __expf(-acc));
        }
    }
}

// Kernel 2: out[p,o] = alpha[n,o]*U[p,o] + V[p,o] (+16*alpha*b_r at p=(0,0))
//   U = (Wr/2)*(x_p + x_flip(p)),  V = (beta.*Wi/2)*(x_p - x_flip(p))
// Phase = FULL WINDOW (96 chans, 96KB fp32 loads): per-CU service time
// (~9.4K cyc under full contention) > compute (~5K cyc), and next-window
// loads are issued BEFORE compute -> vmcnt never drains in the main loop,
// HBM duty ~100% (round-2 regression: per-chunk phases drained vmcnt to 0
// every 32KB -> 40% HBM duty, 12K cyc exposed latency per phase).
// alpha folded per k-chunk via VALU FMA so only acc[6] (24 regs) persists.
__global__ __launch_bounds__(1024, 4) void wfca_main_kernel(
    const float* __restrict__ x,
    const float* __restrict__ w_real, const float* __restrict__ w_imag,
    const float* __restrict__ b_real,
    const float* __restrict__ alpha, const float* __restrict__ beta,
    float* __restrict__ out)
{
    __shared__ __bf16 wr_s[96 * 104];        // 0.5*Wr
    __shared__ __bf16 wi_s[96 * 104];        // 0.5*beta[o]*Wi
    __shared__ __bf16 x_lds[2][256 * 104];   // [pixel][chan], full window, dbuf

    const int t    = threadIdx.x;
    const int blk  = blockIdx.x;             // 256 blocks, 8 windows each
    const int b    = blk >> 5;               // batch
    const int wh   = (blk >> 1) & 15;        // window row
    const int ww0  = (blk & 1) * 8;          // first window col

    const int lane = t & 63;
    const int l16  = lane & 15;
    const int quad = lane >> 4;
    const int wv   = t >> 6;                 // wave id = pixel row h (0..15)
    const int hf   = (16 - wv) & 15;
    const int wf   = (16 - l16) & 15;

    // staging decomposition: sw fast (conflict-friendly LDS writes),
    // g = t>>4 indexes 12 (chan-pair, h) combos per thread.
    const int sw = t & 15;
    const int g  = t >> 4;                   // 0..63

    const float* xb = x + (((size_t)(b * 96)) << 16) + (size_t)(wh * 16) * 256;

    float st0[12], st1[12];                  // staged regs (next window's data)

    auto stage_issue = [&](int win_) {
        const float* xp = xb + (ww0 + win_) * 16 + sw;
        #pragma unroll
        for (int i = 0; i < 12; ++i) {
            int j = g * 12 + i;              // 0..767 = 48 chan-pairs x 16 rows
            int cp = j >> 4, h = j & 15;
            const float* p = xp + (((size_t)(2 * cp)) << 16) + h * 256;
            st0[i] = p[0];
            st1[i] = p[65536];
        }
    };
    auto stage_write = [&](int bufsel) {
        #pragma unroll
        for (int i = 0; i < 12; ++i) {
            int j = g * 12 + i;
            int cp = j >> 4, h = j & 15;
            v2bf pk;
            pk[0] = (__bf16)st0[i];
            pk[1] = (__bf16)st1[i];
            *(v2bf*)&x_lds[bufsel][(h * 16 + sw) * 104 + 2 * cp] = pk;
        }
    };

    // ---- prologue: issue win0 x loads, then stage weights (covers latency) ----
    stage_issue(0);
    {
        float wrv[9], wiv[9], btv[9];
        #pragma unroll
        for (int r = 0; r < 9; ++r) {
            int idx = t + r * 1024;          // 9*1024 = 9216 = 96*96 exact
            wrv[r] = w_real[idx];
            wiv[r] = w_imag[idx];
            btv[r] = beta[idx / 96];
        }
        #pragma unroll
        for (int r = 0; r < 9; ++r) {
            int idx = t + r * 1024;
            int o = idx / 96, c = idx - o * 96;
            wr_s[o * 104 + c] = (__bf16)(0.5f * wrv[r]);
            wi_s[o * 104 + c] = (__bf16)(0.5f * btv[r] * wiv[r]);
        }
    }
    stage_write(0);
    __syncthreads();

    int cur = 0;
    for (int win = 0; win < 8; ++win) {
        // alpha for this window (issued before staged loads of win+1)
        float af[6];
        #pragma unroll
        for (int n = 0; n < 6; ++n)
            af[n] = alpha[(size_t)(blk * 8 + win) * 96 + n * 16 + l16];

        // issue next window's 96KB BEFORE compute; stays in flight all phase
        if (win < 7) stage_issue(win + 1);

        v4f acc[6];
        #pragma unroll
        for (int n = 0; n < 6; ++n) acc[n] = v4f{0.f, 0.f, 0.f, 0.f};

        const __bf16* xl = x_lds[cur];
        #pragma unroll
        for (int k = 0; k < 3; ++k) {
            const int c0 = k * 32;
            v8bf a_x = *(const v8bf*)&xl[(wv * 16 + l16) * 104 + c0 + quad * 8];
            v8bf a_f = *(const v8bf*)&xl[(hf * 16 + wf) * 104 + c0 + quad * 8];
            // exact bf16 negation of flipped fragment (sign-bit XOR)
            v4u fu = __builtin_bit_cast(v4u, a_f);
            const v4u sm = {0x80008000u, 0x80008000u, 0x80008000u, 0x80008000u};
            v8bf a_fn = __builtin_bit_cast(v8bf, fu ^ sm);

            #pragma unroll
            for (int n = 0; n < 6; ++n) {
                v8bf bwr = *(const v8bf*)&wr_s[(n * 16 + l16) * 104 + c0 + quad * 8];
                v8bf bwi = *(const v8bf*)&wi_s[(n * 16 + l16) * 104 + c0 + quad * 8];
                // Wi part accumulates straight into acc
                acc[n] = __builtin_amdgcn_mfma_f32_16x16x32_bf16(a_x,  bwi, acc[n], 0, 0, 0);
                acc[n] = __builtin_amdgcn_mfma_f32_16x16x32_bf16(a_fn, bwi, acc[n], 0, 0, 0);
                // Wr part into a transient, then alpha-scaled VALU FMA
                v4f utmp = __builtin_amdgcn_mfma_f32_16x16x32_bf16(
                               a_x, bwr, v4f{0.f, 0.f, 0.f, 0.f}, 0, 0, 0);
                utmp = __builtin_amdgcn_mfma_f32_16x16x32_bf16(a_f, bwr, utmp, 0, 0, 0);
                #pragma unroll
                for (int r = 0; r < 4; ++r) acc[n][r] += af[n] * utmp[r];
            }
        }

        // epilogue: C/D layout col=l16 (out-ch), row=quad*4+r (= w coord)
        {
            const int col = (ww0 + win) * 16;
            #pragma unroll
            for (int n = 0; n < 6; ++n) {
                const int o = n * 16 + l16;
                v4f v = acc[n];
                if (wv == 0 && quad == 0) {
                    // bias delta at (0,0): IFFT of const b_r over bins = 16*b_r
                    v[0] += 16.f * af[n] * b_real[o];
                }
                size_t idx = (((size_t)(b * 96 + o)) * 256 + wh * 16 + wv) * 256
                             + col + quad * 4;
                *(v4f*)(out + idx) = v;
            }
        }

        // write-late: staged regs -> other buffer (vmcnt wait covered by compute)
        if (win < 7) {
            stage_write(cur ^ 1);
            __syncthreads();
            cur ^= 1;
        }
    }
}

extern "C" void kernel_launch(void* const* d_in, const int* in_sizes, int n_in,
                              void* d_out, int out_size, void* d_ws, size_t ws_size,
                              hipStream_t stream) {
    const float* x      = (const float*)d_in[0];
    const float* w_real = (const float*)d_in[1];
    const float* b_real = (const float*)d_in[2];
    const float* w_imag = (const float*)d_in[3];
    const float* b_imag = (const float*)d_in[4];
    const float* car_w1 = (const float*)d_in[5];
    const float* car_b1 = (const float*)d_in[6];
    const float* car_w2 = (const float*)d_in[7];
    const float* car_b2 = (const float*)d_in[8];
    const float* cai_w1 = (const float*)d_in[9];
    const float* cai_b1 = (const float*)d_in[10];
    const float* cai_w2 = (const float*)d_in[11];
    const float* cai_b2 = (const float*)d_in[12];
    float* out = (float*)d_out;

    float* alpha = (float*)d_ws;            // [2048*96]
    float* beta  = alpha + NWIN * 96;       // [96]

    se_alpha_kernel<<<129, 128, 0, stream>>>(
        x, w_real, b_real, car_w1, car_b1, car_w2, car_b2,
        b_imag, cai_w1, cai_b1, cai_w2, cai_b2, alpha, beta);

    wfca_main_kernel<<<256, 1024, 0, stream>>>(
        x, w_real, w_imag, b_real, alpha, beta, out);
}

// Round 4
// 466.924 us; speedup vs baseline: 1.0826x; 1.0826x over previous
//
#include <hip/hip_runtime.h>
#include <hip/hip_bf16.h>
#include <math.h>

// Problem constants: x [8, 96, 256, 256] fp32, window 16x16 -> 2048 windows.
#define NWIN 2048

typedef __bf16 v8bf __attribute__((ext_vector_type(8)));
typedef __bf16 v2bf __attribute__((ext_vector_type(2)));
typedef float  v4f  __attribute__((ext_vector_type(4)));

// Kernel 1 (batched): block handles 16 windows (one batch-row of windows),
// staging w_real/car_w1/car_w2 ONCE per block.
__global__ __launch_bounds__(128) void se_alpha_kernel(
    const float* __restrict__ x,
    const float* __restrict__ w_real, const float* __restrict__ b_real,
    const float* __restrict__ car_w1, const float* __restrict__ car_b1,
    const float* __restrict__ car_w2, const float* __restrict__ car_b2,
    const float* __restrict__ b_imag,
    const float* __restrict__ cai_w1, const float* __restrict__ cai_b1,
    const float* __restrict__ cai_w2, const float* __restrict__ cai_b2,
    float* __restrict__ alpha, float* __restrict__ beta)
{
    __shared__ float wr_s[96 * 97];   // +1 pad
    __shared__ float w1_s[32 * 97];   // car_w1 [32][96]
    __shared__ float w2_s[96 * 33];   // car_w2 [96][32]
    __shared__ float x0_s[96 * 17];   // corner pixel per chan x 16 windows
    __shared__ float pr_s[16 * 97];   // pooled [win][o]
    __shared__ float h1_s[16 * 33];   // hidden [win][j]
    const int t = threadIdx.x;
    const int blkid = blockIdx.x;

    if (blkid < 128) {
        const int b = blkid >> 4, wh = blkid & 15;
        for (int idx = t; idx < 96 * 96; idx += 128) {
            int o = idx / 96, c = idx - o * 96;
            wr_s[o * 97 + c] = w_real[idx];
        }
        for (int idx = t; idx < 32 * 96; idx += 128) {
            int j = idx / 96, c = idx - j * 96;
            w1_s[j * 97 + c] = car_w1[idx];
        }
        for (int idx = t; idx < 96 * 32; idx += 128) {
            int o = idx >> 5, j = idx & 31;
            w2_s[o * 33 + j] = car_w2[idx];
        }
        for (int idx = t; idx < 96 * 16; idx += 128) {
            int c = idx >> 4, w = idx & 15;
            x0_s[c * 17 + w] = x[(((size_t)(b * 96 + c)) * 256 + wh * 16) * 256 + w * 16];
        }
        __syncthreads();
        #pragma unroll
        for (int i = 0; i < 12; ++i) {
            int p = t + i * 128;            // 96*16 = 1536
            int o = p >> 4, w = p & 15;
            float acc = 0.f;
            #pragma unroll 4
            for (int c = 0; c < 96; ++c) acc += wr_s[o * 97 + c] * x0_s[c * 17 + w];
            pr_s[w * 97 + o] = acc * (1.0f / 16.0f) + b_real[o];
        }
        __syncthreads();
        #pragma unroll
        for (int i = 0; i < 4; ++i) {
            int p = t + i * 128;            // 32*16 = 512
            int j = p >> 4, w = p & 15;
            float acc = car_b1[j];
            #pragma unroll 4
            for (int o = 0; o < 96; ++o) acc += w1_s[j * 97 + o] * pr_s[w * 97 + o];
            h1_s[w * 33 + j] = fmaxf(acc, 0.f);
        }
        __syncthreads();
        #pragma unroll
        for (int i = 0; i < 12; ++i) {
            int p = t + i * 128;            // 96*16 = 1536
            int o = p >> 4, w = p & 15;
            float acc = car_b2[o];
            #pragma unroll
            for (int j = 0; j < 32; ++j) acc += w2_s[o * 33 + j] * h1_s[w * 33 + j];
            int n = (blkid << 4) | w;
            alpha[(size_t)n * 96 + o] = 1.f + 1.f / (1.f + __expf(-acc));
        }
    } else {
        if (t < 32) {
            float acc = cai_b1[t];
            for (int o = 0; o < 96; ++o) acc += cai_w1[t * 96 + o] * b_imag[o];
            h1_s[t] = fmaxf(acc, 0.f);
        }
        __syncthreads();
        if (t < 96) {
            float acc = cai_b2[t];
            for (int j = 0; j < 32; ++j) acc += cai_w2[t * 32 + j] * h1_s[j];
            beta[t] = 1.f + 1.f / (1.f + __expf(-acc));
        }
    }
}

// Kernel 2: out[p,o] = alpha[n,o]*U[p,o] + V[p,o] (+16*alpha*b_r at p=(0,0))
//   U = (Wr/2)*(x_p + x_flip(p)),  V = (beta.*Wi/2)*(x_p - x_flip(p))
// Pipeline: global_load_lds DMA (no staging registers -> regalloc cannot
// sink the prefetch; rounds 1-3 lesson) + counted vmcnt + raw s_barrier,
// 2 chunk-phases in flight (64KB/CU outstanding). x kept fp32 in LDS
// [chan][256]; fragments built via ds_read_b32 + cvt. Global-source
// pre-swizzle (h ^= (chan>>3)&3) + matching XOR on reads -> 2-way banks (free).
// Only VMEM ops in the loop: 2 DMAs/phase + 6 stores/window (exact vmcnt ledger).
__global__ __launch_bounds__(1024, 4) void wfca_main_kernel(
    const float* __restrict__ x,
    const float* __restrict__ w_real, const float* __restrict__ w_imag,
    const float* __restrict__ b_real,
    const float* __restrict__ alpha, const float* __restrict__ beta,
    float* __restrict__ out)
{
    __shared__ __bf16 wr_s[96 * 104];        // 0.5*Wr
    __shared__ __bf16 wi_s[96 * 104];        // 0.5*beta[o]*Wi
    __shared__ float  xf[3][32 * 256];       // fp32 x, buffer = k (chunk id)
    __shared__ float  alpha_s[768];          // 8 windows x 96

    const int t    = threadIdx.x;
    const int blk  = blockIdx.x;             // 256 blocks, 8 windows each
    const int b    = blk >> 5;               // batch
    const int wh   = (blk >> 1) & 15;        // window row
    const int ww0  = (blk & 1) * 8;          // first window col

    const int lane = t & 63;
    const int l16  = lane & 15;
    const int quad = lane >> 4;
    const int wv   = t >> 6;                 // wave id = pixel row h (0..15)
    const int hf   = (16 - wv) & 15;
    const int wf   = (16 - l16) & 15;

    // DMA: each wave loads its 2 channels (1KB each) of chunk k_ for window w_.
    // LDS dest wave-uniform; global h pre-swizzled by (chan_local>>3)&3 so the
    // strided ds_read_b32 fragment reads below are bank-conflict-free.
    auto issue = [&](int w_, int k_) {
        #pragma unroll
        for (int u = 0; u < 2; ++u) {
            const int cl  = 2 * wv + u;                  // chunk-local chan
            const int swz = (cl >> 3) & 3;
            const float* g = x
                + (((size_t)(b * 96 + k_ * 32 + cl)) << 16)
                + (size_t)(wh * 16 + ((lane >> 2) ^ swz)) * 256
                + (ww0 + w_) * 16 + 4 * (lane & 3);
            float* l = &xf[k_][cl * 256];                // wave-uniform base
            __builtin_amdgcn_global_load_lds(
                (const __attribute__((address_space(1))) float*)g,
                (__attribute__((address_space(3))) float*)l, 16, 0, 0);
        }
    };

    // ---- prologue: weights+alpha+b_real staged with NORMAL loads, then one
    //      full __syncthreads (drains everything), then prime the DMA pipe ----
    {
        float wrv[9], wiv[9], btv[9];
        #pragma unroll
        for (int r = 0; r < 9; ++r) {
            int idx = t + r * 1024;          // 9*1024 = 9216 = 96*96 exact
            wrv[r] = w_real[idx];
            wiv[r] = w_imag[idx];
            btv[r] = beta[idx / 96];
        }
        #pragma unroll
        for (int r = 0; r < 9; ++r) {
            int idx = t + r * 1024;
            int o = idx / 96, c = idx - o * 96;
            wr_s[o * 104 + c] = (__bf16)(0.5f * wrv[r]);
            wi_s[o * 104 + c] = (__bf16)(0.5f * btv[r] * wiv[r]);
        }
    }
    if (t < 768) alpha_s[t] = alpha[(size_t)blk * 768 + t];
    float brv[6];
    #pragma unroll
    for (int n = 0; n < 6; ++n) brv[n] = b_real[n * 16 + l16];
    __syncthreads();

    issue(0, 0);
    issue(0, 1);

    const int pxq = (wv * 16 + l16) ^ (quad << 4);   // swizzled own pixel
    const int pfq = (hf * 16 + wf) ^ (quad << 4);    // swizzled flipped pixel

    for (int win = 0; win < 8; ++win) {
        float af[6];
        v4f acc[6];
        #pragma unroll
        for (int n = 0; n < 6; ++n) {
            af[n]  = alpha_s[win * 96 + n * 16 + l16];
            acc[n] = v4f{0.f, 0.f, 0.f, 0.f};
        }
        #pragma unroll
        for (int k = 0; k < 3; ++k) {
            // Counted wait: per-wave VMEM stream = 2 loads/phase + 6 stores at
            // each window end. N = #ops issued after this chunk's 2 loads.
            if (win == 7 && k == 2)      asm volatile("s_waitcnt vmcnt(0)" ::: "memory");
            else if (win == 0 || k == 2) asm volatile("s_waitcnt vmcnt(2)" ::: "memory");
            else                         asm volatile("s_waitcnt vmcnt(8)" ::: "memory");
            __builtin_amdgcn_s_barrier();          // all waves' chunk-k loads landed
            __builtin_amdgcn_sched_barrier(0);

            // issue chunk t+2 (its buffer was consumed last phase; barrier above
            // guarantees every wave is done reading it)
            if (k == 0)      issue(win, 2);
            else if (k == 1) { if (win < 7) issue(win + 1, 0); }
            else             { if (win < 7) issue(win + 1, 1); }

            // fragments from fp32 LDS (conflict-free via swizzle), cvt to bf16
            const float* xk = xf[k];
            float fx[8], ff[8];
            #pragma unroll
            for (int j = 0; j < 8; ++j) {
                fx[j] = xk[(quad * 8 + j) * 256 + pxq];
                ff[j] = xk[(quad * 8 + j) * 256 + pfq];
            }
            v8bf a_x, a_f, a_fn;
            #pragma unroll
            for (int j = 0; j < 8; ++j) {
                a_x[j]  = (__bf16)fx[j];
                a_f[j]  = (__bf16)ff[j];
                a_fn[j] = (__bf16)(-ff[j]);
            }
            const int c0 = k * 32;
            #pragma unroll
            for (int n = 0; n < 6; ++n) {
                v8bf bwr = *(const v8bf*)&wr_s[(n * 16 + l16) * 104 + c0 + quad * 8];
                v8bf bwi = *(const v8bf*)&wi_s[(n * 16 + l16) * 104 + c0 + quad * 8];
                acc[n] = __builtin_amdgcn_mfma_f32_16x16x32_bf16(a_x,  bwi, acc[n], 0, 0, 0);
                acc[n] = __builtin_amdgcn_mfma_f32_16x16x32_bf16(a_fn, bwi, acc[n], 0, 0, 0);
                v4f utmp = __builtin_amdgcn_mfma_f32_16x16x32_bf16(
                               a_x, bwr, v4f{0.f, 0.f, 0.f, 0.f}, 0, 0, 0);
                utmp = __builtin_amdgcn_mfma_f32_16x16x32_bf16(a_f, bwr, utmp, 0, 0, 0);
                #pragma unroll
                for (int r = 0; r < 4; ++r) acc[n][r] += af[n] * utmp[r];
            }
        }

        // epilogue: C/D layout col=l16 (out-ch), row=quad*4+r (= w coord)
        {
            const int col = (ww0 + win) * 16;
            #pragma unroll
            for (int n = 0; n < 6; ++n) {
                const int o = n * 16 + l16;
                v4f v = acc[n];
                if (wv == 0 && quad == 0) {
                    // bias delta at (0,0): IFFT of const b_r over bins = 16*b_r
                    v[0] += 16.f * af[n] * brv[n];
                }
                size_t idx = (((size_t)(b * 96 + o)) * 256 + wh * 16 + wv) * 256
                             + col + quad * 4;
                *(v4f*)(out + idx) = v;
            }
        }
    }
}

extern "C" void kernel_launch(void* const* d_in, const int* in_sizes, int n_in,
                              void* d_out, int out_size, void* d_ws, size_t ws_size,
                              hipStream_t stream) {
    const float* x      = (const float*)d_in[0];
    const float* w_real = (const float*)d_in[1];
    const float* b_real = (const float*)d_in[2];
    const float* w_imag = (const float*)d_in[3];
    const float* b_imag = (const float*)d_in[4];
    const float* car_w1 = (const float*)d_in[5];
    const float* car_b1 = (const float*)d_in[6];
    const float* car_w2 = (const float*)d_in[7];
    const float* car_b2 = (const float*)d_in[8];
    const float* cai_w1 = (const float*)d_in[9];
    const float* cai_b1 = (const float*)d_in[10];
    const float* cai_w2 = (const float*)d_in[11];
    const float* cai_b2 = (const float*)d_in[12];
    float* out = (float*)d_out;

    float* alpha = (float*)d_ws;            // [2048*96]
    float* beta  = alpha + NWIN * 96;       // [96]

    se_alpha_kernel<<<129, 128, 0, stream>>>(
        x, w_real, b_real, car_w1, car_b1, car_w2, car_b2,
        b_imag, cai_w1, cai_b1, cai_w2, cai_b2, alpha, beta);

    wfca_main_kernel<<<256, 1024, 0, stream>>>(
        x, w_real, w_imag, b_real, alpha, beta, out);
}

// Round 5
// 419.182 us; speedup vs baseline: 1.2059x; 1.1139x over previous
//
#include <hip/hip_runtime.h>
#include <hip/hip_bf16.h>
#include <math.h>

// Problem constants: x [8, 96, 256, 256] fp32, window 16x16 -> 2048 windows.
#define NWIN 2048

typedef __bf16 v8bf __attribute__((ext_vector_type(8)));
typedef float  v4f  __attribute__((ext_vector_type(4)));

// Kernel 1 (batched): block handles 16 windows (one batch-row of windows),
// staging w_real/car_w1/car_w2 ONCE per block.
__global__ __launch_bounds__(128) void se_alpha_kernel(
    const float* __restrict__ x,
    const float* __restrict__ w_real, const float* __restrict__ b_real,
    const float* __restrict__ car_w1, const float* __restrict__ car_b1,
    const float* __restrict__ car_w2, const float* __restrict__ car_b2,
    const float* __restrict__ b_imag,
    const float* __restrict__ cai_w1, const float* __restrict__ cai_b1,
    const float* __restrict__ cai_w2, const float* __restrict__ cai_b2,
    float* __restrict__ alpha, float* __restrict__ beta)
{
    __shared__ float wr_s[96 * 97];   // +1 pad
    __shared__ float w1_s[32 * 97];   // car_w1 [32][96]
    __shared__ float w2_s[96 * 33];   // car_w2 [96][32]
    __shared__ float x0_s[96 * 17];   // corner pixel per chan x 16 windows
    __shared__ float pr_s[16 * 97];   // pooled [win][o]
    __shared__ float h1_s[16 * 33];   // hidden [win][j]
    const int t = threadIdx.x;
    const int blkid = blockIdx.x;

    if (blkid < 128) {
        const int b = blkid >> 4, wh = blkid & 15;
        for (int idx = t; idx < 96 * 96; idx += 128) {
            int o = idx / 96, c = idx - o * 96;
            wr_s[o * 97 + c] = w_real[idx];
        }
        for (int idx = t; idx < 32 * 96; idx += 128) {
            int j = idx / 96, c = idx - j * 96;
            w1_s[j * 97 + c] = car_w1[idx];
        }
        for (int idx = t; idx < 96 * 32; idx += 128) {
            int o = idx >> 5, j = idx & 31;
            w2_s[o * 33 + j] = car_w2[idx];
        }
        for (int idx = t; idx < 96 * 16; idx += 128) {
            int c = idx >> 4, w = idx & 15;
            x0_s[c * 17 + w] = x[(((size_t)(b * 96 + c)) * 256 + wh * 16) * 256 + w * 16];
        }
        __syncthreads();
        #pragma unroll
        for (int i = 0; i < 12; ++i) {
            int p = t + i * 128;            // 96*16 = 1536
            int o = p >> 4, w = p & 15;
            float acc = 0.f;
            #pragma unroll 4
            for (int c = 0; c < 96; ++c) acc += wr_s[o * 97 + c] * x0_s[c * 17 + w];
            pr_s[w * 97 + o] = acc * (1.0f / 16.0f) + b_real[o];
        }
        __syncthreads();
        #pragma unroll
        for (int i = 0; i < 4; ++i) {
            int p = t + i * 128;            // 32*16 = 512
            int j = p >> 4, w = p & 15;
            float acc = car_b1[j];
            #pragma unroll 4
            for (int o = 0; o < 96; ++o) acc += w1_s[j * 97 + o] * pr_s[w * 97 + o];
            h1_s[w * 33 + j] = fmaxf(acc, 0.f);
        }
        __syncthreads();
        #pragma unroll
        for (int i = 0; i < 12; ++i) {
            int p = t + i * 128;            // 96*16 = 1536
            int o = p >> 4, w = p & 15;
            float acc = car_b2[o];
            #pragma unroll
            for (int j = 0; j < 32; ++j) acc += w2_s[o * 33 + j] * h1_s[w * 33 + j];
            int n = (blkid << 4) | w;
            alpha[(size_t)n * 96 + o] = 1.f + 1.f / (1.f + __expf(-acc));
        }
    } else {
        if (t < 32) {
            float acc = cai_b1[t];
            for (int o = 0; o < 96; ++o) acc += cai_w1[t * 96 + o] * b_imag[o];
            h1_s[t] = fmaxf(acc, 0.f);
        }
        __syncthreads();
        if (t < 96) {
            float acc = cai_b2[t];
            for (int j = 0; j < 32; ++j) acc += cai_w2[t * 32 + j] * h1_s[j];
            beta[t] = 1.f + 1.f / (1.f + __expf(-acc));
        }
    }
}

// Kernel 2 (row-pair tiling for CONTIGUOUS HBM access):
//   out[p,o] = alpha[n,o]*U[p,o] + V[p,o] (+16*alpha*b_r at window pixel (0,0))
//   U = (Wr/2)*(x_p + x_flip(p)),  V = (beta.*Wi/2)*(x_p - x_flip(p))
// flip couples only image-row pairs {h,16-h} ({0},{8} self-paired), so:
// block = (batch, window-row, col-half) -> 256 blocks; processes 4 row-pairs
// K-complete each (acc stays 24 regs). DMA per chunk-phase = 32 chans x
// 2 rows x 128 contiguous cols: 512B runs, full cache lines (rounds 0-4 all
// plateaued at 2.55 TB/s with 64B-at-1KB-stride scatter -> DRAM-locality
// limited; schedule changes were neutral). Chan-parity XOR-16 pre-swizzle of
// the GLOBAL source col keeps strided LDS frag reads 2-way-bank-free while
// fetches stay 64B-dense. Counted-vmcnt 3-buffer pipeline as round 4.
__global__ __launch_bounds__(1024, 4) void wfca_main_kernel(
    const float* __restrict__ x,
    const float* __restrict__ w_real, const float* __restrict__ w_imag,
    const float* __restrict__ b_real,
    const float* __restrict__ alpha, const float* __restrict__ beta,
    float* __restrict__ out)
{
    __shared__ __bf16 wr_s[96 * 104];        // 0.5*Wr
    __shared__ __bf16 wi_s[96 * 104];        // 0.5*beta[o]*Wi
    __shared__ float  xf[3][32 * 256];       // fp32 x: [chunk buf][chan][2 rows x 128 cols]
    __shared__ float  alpha_s[768];          // 8 windows x 96

    const int t    = threadIdx.x;
    const int blk  = blockIdx.x;             // 256 = b(3) | wh(4) | ch(1)
    const int b    = blk >> 5;               // batch
    const int wh   = (blk >> 1) & 15;        // window row
    const int ch   = blk & 1;                // column half (8 windows)

    const int lane = t & 63;
    const int l16  = lane & 15;
    const int quad = lane >> 4;
    const int wv   = t >> 6;                 // 0..15
    const int r2m  = wv >> 3;                // wave's row within pair (0=lo,1=hi)
    const int wm   = wv & 7;                 // wave's window within half

    // fragment cols (XOR-16 de-swizzle matches the source pre-swizzle below)
    const int pxq = (wm * 16 + l16) ^ ((quad & 1) << 4);
    const int pfq = (wm * 16 + ((16 - l16) & 15)) ^ ((quad & 1) << 4);

    // DMA: wave loads 2 chans; per chan one instr = rows {h_lo,h_hi} x 512B.
    // Global col pre-swizzled by chan parity so LDS stays linear (m173 pattern).
    auto issue = [&](int rp_, int k_, int buf_) {
        const int hl = rp_;
        const int hh = (rp_ == 0) ? 8 : 16 - rp_;
        #pragma unroll
        for (int u = 0; u < 2; ++u) {
            const int c    = 2 * wv + u;                 // chunk-local chan
            const int swz  = ((c >> 3) & 1) << 4;
            const int row  = (lane >> 5) ? hh : hl;
            const int colg = (4 * (lane & 31)) ^ swz;
            const float* g = x + (((size_t)(b * 96 + k_ * 32 + c)) << 16)
                           + (size_t)(wh * 16 + row) * 256 + ch * 128 + colg;
            float* l = &xf[buf_][c * 256];               // wave-uniform base
            __builtin_amdgcn_global_load_lds(
                (const __attribute__((address_space(1))) float*)g,
                (__attribute__((address_space(3))) float*)l, 16, 0, 0);
        }
    };

    // ---- prologue: weights+alpha+b_real via normal loads, full sync, prime ----
    {
        float wrv[9], wiv[9], btv[9];
        #pragma unroll
        for (int r = 0; r < 9; ++r) {
            int idx = t + r * 1024;          // 9*1024 = 9216 = 96*96 exact
            wrv[r] = w_real[idx];
            wiv[r] = w_imag[idx];
            btv[r] = beta[idx / 96];
        }
        #pragma unroll
        for (int r = 0; r < 9; ++r) {
            int idx = t + r * 1024;
            int o = idx / 96, c = idx - o * 96;
            wr_s[o * 104 + c] = (__bf16)(0.5f * wrv[r]);
            wi_s[o * 104 + c] = (__bf16)(0.5f * btv[r] * wiv[r]);
        }
    }
    if (t < 768) {
        int w = t / 96, o = t - w * 96;
        alpha_s[t] = alpha[(size_t)(b * 256 + wh * 16 + ch * 8 + w) * 96 + o];
    }
    float brv[6];
    #pragma unroll
    for (int n = 0; n < 6; ++n) brv[n] = b_real[n * 16 + l16];
    __syncthreads();                          // drains all vmcnt: clean ledger

    issue(0, 0, 0);
    issue(0, 1, 1);

    for (int rp = 0; rp < 8; ++rp) {
        const int h_lo   = rp;
        const int h_hi   = (rp == 0) ? 8 : 16 - rp;
        const int h_out  = r2m ? h_hi : h_lo;
        const int flipr2 = (rp == 0) ? r2m : 1 - r2m;

        float af[6];
        v4f acc[6];
        #pragma unroll
        for (int n = 0; n < 6; ++n) {
            af[n]  = alpha_s[wm * 96 + n * 16 + l16];
            acc[n] = v4f{0.f, 0.f, 0.f, 0.f};
        }
        #pragma unroll
        for (int k = 0; k < 3; ++k) {
            // counted wait: per-wave stream = 2 loads/phase + 6 stores/row-pair
            if (rp == 7 && k == 2)      asm volatile("s_waitcnt vmcnt(0)" ::: "memory");
            else if (rp == 0 || k == 2) asm volatile("s_waitcnt vmcnt(2)" ::: "memory");
            else                        asm volatile("s_waitcnt vmcnt(8)" ::: "memory");
            __builtin_amdgcn_s_barrier();     // chunk-k landed for all waves
            __builtin_amdgcn_sched_barrier(0);

            // issue chunk 2 phases ahead (its buffer freed by the barrier above)
            if (k == 0)      issue(rp, 2, 2);
            else if (k == 1) { if (rp < 7) issue(rp + 1, 0, 0); }
            else             { if (rp < 7) issue(rp + 1, 1, 1); }

            // fragments from fp32 LDS (2-way banks via swizzle), cvt to bf16
            const float* xk = xf[k];
            float fxv[8], ffv[8];
            #pragma unroll
            for (int j = 0; j < 8; ++j) {
                fxv[j] = xk[(quad * 8 + j) * 256 + r2m * 128 + pxq];
                ffv[j] = xk[(quad * 8 + j) * 256 + flipr2 * 128 + pfq];
            }
            v8bf a_x, a_f, a_fn;
            #pragma unroll
            for (int j = 0; j < 8; ++j) {
                a_x[j]  = (__bf16)fxv[j];
                a_f[j]  = (__bf16)ffv[j];
                a_fn[j] = (__bf16)(-ffv[j]);
            }
            const int c0 = k * 32;
            #pragma unroll
            for (int n = 0; n < 6; ++n) {
                v8bf bwr = *(const v8bf*)&wr_s[(n * 16 + l16) * 104 + c0 + quad * 8];
                v8bf bwi = *(const v8bf*)&wi_s[(n * 16 + l16) * 104 + c0 + quad * 8];
                acc[n] = __builtin_amdgcn_mfma_f32_16x16x32_bf16(a_x,  bwi, acc[n], 0, 0, 0);
                acc[n] = __builtin_amdgcn_mfma_f32_16x16x32_bf16(a_fn, bwi, acc[n], 0, 0, 0);
                v4f utmp = __builtin_amdgcn_mfma_f32_16x16x32_bf16(
                               a_x, bwr, v4f{0.f, 0.f, 0.f, 0.f}, 0, 0, 0);
                utmp = __builtin_amdgcn_mfma_f32_16x16x32_bf16(a_f, bwr, utmp, 0, 0, 0);
                #pragma unroll
                for (int r = 0; r < 4; ++r) acc[n][r] += af[n] * utmp[r];
            }
        }

        // epilogue: C/D col=l16 (out-chan), row=quad*4+r (= pixel col in window)
        {
            #pragma unroll
            for (int n = 0; n < 6; ++n) {
                const int o = n * 16 + l16;
                v4f v = acc[n];
                if (h_out == 0 && quad == 0) {
                    // bias delta at window pixel (0,0): IFFT of const b_r = 16*b_r
                    v[0] += 16.f * af[n] * brv[n];
                }
                size_t idx = (((size_t)(b * 96 + o)) * 256 + wh * 16 + h_out) * 256
                             + ch * 128 + wm * 16 + quad * 4;
                *(v4f*)(out + idx) = v;
            }
        }
    }
}

extern "C" void kernel_launch(void* const* d_in, const int* in_sizes, int n_in,
                              void* d_out, int out_size, void* d_ws, size_t ws_size,
                              hipStream_t stream) {
    const float* x      = (const float*)d_in[0];
    const float* w_real = (const float*)d_in[1];
    const float* b_real = (const float*)d_in[2];
    const float* w_imag = (const float*)d_in[3];
    const float* b_imag = (const float*)d_in[4];
    const float* car_w1 = (const float*)d_in[5];
    const float* car_b1 = (const float*)d_in[6];
    const float* car_w2 = (const float*)d_in[7];
    const float* car_b2 = (const float*)d_in[8];
    const float* cai_w1 = (const float*)d_in[9];
    const float* cai_b1 = (const float*)d_in[10];
    const float* cai_w2 = (const float*)d_in[11];
    const float* cai_b2 = (const float*)d_in[12];
    float* out = (float*)d_out;

    float* alpha = (float*)d_ws;            // [2048*96]
    float* beta  = alpha + NWIN * 96;       // [96]

    se_alpha_kernel<<<129, 128, 0, stream>>>(
        x, w_real, b_real, car_w1, car_b1, car_w2, car_b2,
        b_imag, cai_w1, cai_b1, cai_w2, cai_b2, alpha, beta);

    wfca_main_kernel<<<256, 1024, 0, stream>>>(
        x, w_real, w_imag, b_real, alpha, beta, out);
}